// Round 1
// baseline (12422.560 us; speedup 1.0000x reference)
//
#include <hip/hip_runtime.h>

#define NNODES 50000
#define NEDGES 800000
#define NGRAPHS 32
#define NSPEC 10
#define CC 32
#define RH 64
#define NB 8

#define EBLK 128

// ---------------- embed: h[n][c] = sum_s attrs[n][s] * Wemb[s][c] ----------------
__global__ __launch_bounds__(256) void embed_kernel(const float* __restrict__ attrs,
                                                    const float* __restrict__ Wemb,
                                                    float* __restrict__ h) {
    int t = blockIdx.x * 256 + threadIdx.x;
    if (t >= NNODES * CC) return;
    int n = t >> 5, c = t & 31;
    float acc = 0.f;
#pragma unroll
    for (int s = 0; s < NSPEC; ++s) acc += attrs[n * NSPEC + s] * Wemb[s * CC + c];
    h[t] = acc;
}

// ---------------- edge kernel: geometry + radial MLP + SH + scatter ----------------
__global__ __launch_bounds__(EBLK) void edge_kernel(
    const float* __restrict__ pos, const float* __restrict__ shifts,
    const int* __restrict__ eidx,
    const float* __restrict__ rW1, const float* __restrict__ rb1,
    const float* __restrict__ rW2, const float* __restrict__ rb2,
    const float* __restrict__ rW3,
    const float* __restrict__ h, float* __restrict__ A) {
    __shared__ float act[RH * EBLK];  // per-thread private columns: act[k*EBLK+tid]
    const int tid = threadIdx.x;
    const int e = blockIdx.x * EBLK + tid;

    const int snd = eidx[e];
    const int rcv = eidx[NEDGES + e];

    const float vx = pos[rcv * 3 + 0] - pos[snd * 3 + 0] + shifts[e * 3 + 0];
    const float vy = pos[rcv * 3 + 1] - pos[snd * 3 + 1] + shifts[e * 3 + 1];
    const float vz = pos[rcv * 3 + 2] - pos[snd * 3 + 2] + shifts[e * 3 + 2];
    const float r = sqrtf(vx * vx + vy * vy + vz * vz);
    const float safe_r = fmaxf(r, 1e-9f);
    const float rinv = 1.f / safe_r;
    const float ux = vx * rinv, uy = vy * rinv, uz = vz * rinv;

    // radial basis: sqrt(2/5)*sin(n*pi*r/5)/r * fcut(u)
    const float u = r * 0.2f;
    const float u2 = u * u;
    const float u6 = u2 * u2 * u2;
    const float u7 = u6 * u;
    const float u8 = u7 * u;
    float fcut = 1.f - 28.f * u6 + 48.f * u7 - 21.f * u8;
    fcut = (u < 1.f) ? fcut : 0.f;
    const float pref = 0.632455532f * rinv * fcut;  // sqrt(2/RMAX)/safe_r*fcut
    float rb[NB];
#pragma unroll
    for (int k = 0; k < NB; ++k) {
        const float fk = (float)(k + 1) * 0.628318530718f;  // n*pi/RMAX
        rb[k] = __sinf(fk * safe_r) * pref;
    }

    // ---- layer 1: h1 = silu(rb @ rW1 + rb1), rW1 is [8][64] (uniform -> s_load)
    {
        float h1[RH];
#pragma unroll
        for (int j = 0; j < RH; ++j) h1[j] = rb1[j];
#pragma unroll
        for (int k = 0; k < NB; ++k) {
            const float* w = rW1 + k * RH;
#pragma unroll
            for (int j = 0; j < RH; ++j) h1[j] = fmaf(rb[k], w[j], h1[j]);
        }
#pragma unroll
        for (int j = 0; j < RH; ++j) {
            const float x = h1[j];
            act[j * EBLK + tid] = x / (1.f + __expf(-x));
        }
    }

    // ---- layer 2: h2 = silu(h1 @ rW2 + rb2), h1 read from LDS (runtime k)
    {
        float h2[RH];
#pragma unroll
        for (int j = 0; j < RH; ++j) h2[j] = rb2[j];
        for (int k = 0; k < RH; ++k) {
            const float hk = act[k * EBLK + tid];
            const float* w = rW2 + k * RH;
#pragma unroll
            for (int j = 0; j < RH; ++j) h2[j] = fmaf(hk, w[j], h2[j]);
        }
#pragma unroll
        for (int j = 0; j < RH; ++j) {
            const float x = h2[j];
            act[j * EBLK + tid] = x / (1.f + __expf(-x));  // overwrite: private slot, no barrier
        }
    }

    // spherical harmonics (component norm)
    float Y[9];
    {
        const float s3 = 1.7320508075688772f;
        const float s15 = 3.872983346207417f;
        const float s15h = 1.9364916731037085f;
        const float s5h = 1.118033988749895f;
        Y[0] = 1.f;
        Y[1] = s3 * ux; Y[2] = s3 * uy; Y[3] = s3 * uz;
        Y[4] = s15 * ux * uy; Y[5] = s15 * uy * uz;
        Y[6] = s5h * (3.f * uz * uz - 1.f);
        Y[7] = s15 * ux * uz;
        Y[8] = s15h * (ux * ux - uy * uy);
    }

    // ---- layer 3 (R = h2 @ rW3, reshaped [32][3]) + message + scatter
    float* Abase = A + (size_t)rcv * (CC * 9);
    const float* hrow = h + (size_t)snd * CC;
    for (int cc = 0; cc < 4; ++cc) {  // 4 chunks of 8 channels
        const float4 hsA = *(const float4*)(hrow + cc * 8);
        const float4 hsB = *(const float4*)(hrow + cc * 8 + 4);
        const float hsv[8] = {hsA.x, hsA.y, hsA.z, hsA.w, hsB.x, hsB.y, hsB.z, hsB.w};
        float acc[8][3];
#pragma unroll
        for (int c = 0; c < 8; ++c)
#pragma unroll
            for (int l = 0; l < 3; ++l) acc[c][l] = 0.f;
        for (int k = 0; k < RH; ++k) {
            const float hk = act[k * EBLK + tid];
            const float* w = rW3 + k * 96 + cc * 24;  // uniform -> s_load
#pragma unroll
            for (int c = 0; c < 8; ++c) {
#pragma unroll
                for (int l = 0; l < 3; ++l) acc[c][l] = fmaf(hk, w[c * 3 + l], acc[c][l]);
            }
        }
#pragma unroll
        for (int c = 0; c < 8; ++c) {
            const float g0 = acc[c][0] * hsv[c];
            const float g1 = acc[c][1] * hsv[c];
            const float g2 = acc[c][2] * hsv[c];
            float* Ap = Abase + (cc * 8 + c) * 9;
            atomicAdd(Ap + 0, g0 * Y[0]);
            atomicAdd(Ap + 1, g1 * Y[1]);
            atomicAdd(Ap + 2, g1 * Y[2]);
            atomicAdd(Ap + 3, g1 * Y[3]);
            atomicAdd(Ap + 4, g2 * Y[4]);
            atomicAdd(Ap + 5, g2 * Y[5]);
            atomicAdd(Ap + 6, g2 * Y[6]);
            atomicAdd(Ap + 7, g2 * Y[7]);
            atomicAdd(Ap + 8, g2 * Y[8]);
        }
    }
}

// ---------------- node kernel: A -> A2 -> B -> node_e -> graph_e ----------------
__global__ __launch_bounds__(256) void node_kernel(
    const float* __restrict__ A, const float* __restrict__ Wmix,
    const float* __restrict__ wquad, const float* __restrict__ Wread,
    const float* __restrict__ attrs, const float* __restrict__ ae,
    const int* __restrict__ batch, float* __restrict__ out) {
    __shared__ float Ald[8][CC * 9];
    const int t = threadIdx.x;
    const int ln = t >> 5;   // local node 0..7
    const int d = t & 31;    // channel
    const int n = blockIdx.x * 8 + ln;

    const float* Arow = A + (size_t)n * (CC * 9);
#pragma unroll
    for (int i = 0; i < 9; ++i) Ald[ln][d + 32 * i] = Arow[d + 32 * i] * (1.f / 16.f);
    __syncthreads();

    float A2[9];
#pragma unroll
    for (int m = 0; m < 9; ++m) {
        const int l = (m == 0) ? 0 : ((m < 4) ? 1 : 2);
        float acc = 0.f;
#pragma unroll
        for (int c = 0; c < CC; ++c)
            acc = fmaf(Wmix[(l * CC + c) * CC + d], Ald[ln][c * 9 + m], acc);
        A2[m] = acc;
    }

    const float q0 = wquad[0], q1 = wquad[1], q2 = wquad[2];
    const float n0 = A2[0] * A2[0];
    const float n1 = A2[1] * A2[1] + A2[2] * A2[2] + A2[3] * A2[3];
    const float n2 = A2[4] * A2[4] + A2[5] * A2[5] + A2[6] * A2[6] + A2[7] * A2[7] + A2[8] * A2[8];
    const float B = A2[0] + n0 * q0 + n1 * q1 + n2 * q2;

    float v = B * Wread[d];
#pragma unroll
    for (int off = 16; off; off >>= 1) v += __shfl_xor(v, off, 32);

    if (d == 0) {
        float ne = v;
#pragma unroll
        for (int s = 0; s < NSPEC; ++s) ne += attrs[n * NSPEC + s] * ae[s];
        atomicAdd(&out[batch[n]], ne);
    }
}

extern "C" void kernel_launch(void* const* d_in, const int* in_sizes, int n_in,
                              void* d_out, int out_size, void* d_ws, size_t ws_size,
                              hipStream_t stream) {
    const float* attrs  = (const float*)d_in[0];
    const float* pos    = (const float*)d_in[1];
    const float* shifts = (const float*)d_in[2];
    const float* Wemb   = (const float*)d_in[3];
    const float* rW1    = (const float*)d_in[4];
    const float* rb1    = (const float*)d_in[5];
    const float* rW2    = (const float*)d_in[6];
    const float* rb2    = (const float*)d_in[7];
    const float* rW3    = (const float*)d_in[8];
    const float* Wmix   = (const float*)d_in[9];
    const float* wquad  = (const float*)d_in[10];
    const float* Wread  = (const float*)d_in[11];
    const float* ae     = (const float*)d_in[12];
    const int* eidx     = (const int*)d_in[13];
    const int* batch    = (const int*)d_in[14];
    float* out = (float*)d_out;

    float* A = (float*)d_ws;                               // 50000*288*4 = 57.6 MB
    float* h = (float*)((char*)d_ws + (size_t)NNODES * CC * 9 * 4);  // 6.4 MB

    hipMemsetAsync(A, 0, (size_t)NNODES * CC * 9 * sizeof(float), stream);
    hipMemsetAsync(out, 0, NGRAPHS * sizeof(float), stream);

    embed_kernel<<<(NNODES * CC) / 256, 256, 0, stream>>>(attrs, Wemb, h);
    edge_kernel<<<NEDGES / EBLK, EBLK, 0, stream>>>(pos, shifts, eidx, rW1, rb1, rW2, rb2,
                                                    rW3, h, A);
    node_kernel<<<NNODES / 8, 256, 0, stream>>>(A, Wmix, wquad, Wread, attrs, ae, batch, out);
}